// Round 1
// baseline (1071.789 us; speedup 1.0000x reference)
//
#include <hip/hip_runtime.h>
#include <hip/hip_bf16.h>
#include <math.h>

#define BB 512
#define CC 50

// ---------------- zero-fill out[0 : 512*692*10) ----------------
__global__ void k_zero(float* __restrict__ out, int n4) {
  int i = blockIdx.x * 256 + threadIdx.x;
  if (i < n4) {
    float4 z = {0.f, 0.f, 0.f, 0.f};
    ((float4*)out)[i] = z;
  }
}

// ---------------- conv1 (1->50, 3x3) + relu + pool2 -> h1[512,50,13,13] ----------------
__global__ void k_conv1(const float* __restrict__ x, const float* __restrict__ w,
                        const float* __restrict__ bias, float* __restrict__ h1) {
  int idx = blockIdx.x * 256 + threadIdx.x;
  if (idx >= BB * CC * 169) return;
  int b = idx / (CC * 169);
  int rem = idx % (CC * 169);
  int c = rem / 169;
  int p = rem % 169;
  int py = p / 13, px = p % 13;
  const float* xi = x + b * 784;
  float wr[9];
#pragma unroll
  for (int i = 0; i < 9; i++) wr[i] = w[c * 9 + i];
  float m = -INFINITY;
#pragma unroll
  for (int dy = 0; dy < 2; dy++)
#pragma unroll
    for (int dx = 0; dx < 2; dx++) {
      int y0 = 2 * py + dy, x0 = 2 * px + dx;
      float s = 0.f;
#pragma unroll
      for (int ky = 0; ky < 3; ky++)
#pragma unroll
        for (int kx = 0; kx < 3; kx++)
          s += xi[(y0 + ky) * 28 + x0 + kx] * wr[ky * 3 + kx];
      m = fmaxf(m, s);
    }
  h1[idx] = fmaxf(m + bias[c], 0.f);
}

// ---------------- router 1: argmax over 3 logits of h1 flat (8450) ----------------
__global__ void k_d1(const float* __restrict__ h1, const float* __restrict__ w,
                     const float* __restrict__ bias, int* __restrict__ d1i,
                     float* __restrict__ outd1) {
  int b = blockIdx.x, t = threadIdx.x;
  const float* hb = h1 + b * 8450;
  float s0 = 0.f, s1 = 0.f, s2 = 0.f;
  for (int i = t; i < 8450; i += 256) {
    float v = hb[i];
    s0 += v * w[i];
    s1 += v * w[8450 + i];
    s2 += v * w[16900 + i];
  }
#pragma unroll
  for (int off = 32; off >= 1; off >>= 1) {
    s0 += __shfl_down(s0, off);
    s1 += __shfl_down(s1, off);
    s2 += __shfl_down(s2, off);
  }
  __shared__ float red[4][3];
  if ((t & 63) == 0) { red[t >> 6][0] = s0; red[t >> 6][1] = s1; red[t >> 6][2] = s2; }
  __syncthreads();
  if (t == 0) {
    float l0 = bias[0], l1v = bias[1], l2v = bias[2];
    for (int wv = 0; wv < 4; wv++) { l0 += red[wv][0]; l1v += red[wv][1]; l2v += red[wv][2]; }
    int idx = 0; float best = l0;
    if (l1v > best) { best = l1v; idx = 1; }
    if (l2v > best) { best = l2v; idx = 2; }
    d1i[b] = idx;
    outd1[b] = (float)idx;
  }
}

// ---------------- router 2: argmax over 2 logits of h2 flat (1250) ----------------
__global__ void k_d2(const float* __restrict__ h2, const float* __restrict__ w,
                     const float* __restrict__ bias, int* __restrict__ d2i,
                     float* __restrict__ outd2) {
  int b = blockIdx.x, t = threadIdx.x;
  const float* hb = h2 + b * 1250;
  float s0 = 0.f, s1 = 0.f;
  for (int i = t; i < 1250; i += 256) {
    float v = hb[i];
    s0 += v * w[i];
    s1 += v * w[1250 + i];
  }
#pragma unroll
  for (int off = 32; off >= 1; off >>= 1) {
    s0 += __shfl_down(s0, off);
    s1 += __shfl_down(s1, off);
  }
  __shared__ float red[4][2];
  if ((t & 63) == 0) { red[t >> 6][0] = s0; red[t >> 6][1] = s1; }
  __syncthreads();
  if (t == 0) {
    float l0 = bias[0] + red[0][0] + red[1][0] + red[2][0] + red[3][0];
    float l1v = bias[1] + red[0][1] + red[1][1] + red[2][1] + red[3][1];
    int idx = (l1v > l0) ? 1 : 0;
    d2i[b] = idx;
    outd2[b] = (float)idx;
  }
}

// ---------------- pool7 of h1 (top-left 7x7 window only, VALID) ----------------
__global__ void k_p7(const float* __restrict__ h1, float* __restrict__ p7) {
  int idx = blockIdx.x * 256 + threadIdx.x;
  if (idx >= BB * CC) return;
  int b = idx / CC, c = idx % CC;
  const float* hp = h1 + b * 8450 + c * 169;
  float m = -INFINITY;
#pragma unroll
  for (int y = 0; y < 7; y++)
#pragma unroll
    for (int x = 0; x < 7; x++) m = fmaxf(m, hp[y * 13 + x]);
  p7[idx] = m;
}

// ---------------- 50ch 3x3 conv (13x13 -> 11x11) + relu + pool2 -> [50,5,5] ----------------
// MODE 0: always (conv2 on h1 -> h2); MODE 1: only d1==1 (conv3 on c33 -> c3d)
template <int MODE>
__global__ __launch_bounds__(256) void k_conv5(const float* __restrict__ in,
                                               const float* __restrict__ w,
                                               const float* __restrict__ bias,
                                               const int* __restrict__ d1i,
                                               float* __restrict__ out) {
  int b = blockIdx.x;
  if (MODE == 1 && d1i[b] != 1) return;
  __shared__ float sh[8450];
  for (int i = threadIdx.x; i < 8450; i += 256) sh[i] = in[b * 8450 + i];
  __syncthreads();
  int t = threadIdx.x;
  if (t >= 250) return;
  int oc = t / 5, py = t % 5;
  float acc[5][4];
#pragma unroll
  for (int i = 0; i < 5; i++)
#pragma unroll
    for (int j = 0; j < 4; j++) acc[i][j] = 0.f;
  const float* wb = w + oc * 450;
  for (int ic = 0; ic < 50; ic++) {
    float wv[9];
#pragma unroll
    for (int i = 0; i < 9; i++) wv[i] = wb[ic * 9 + i];
    float r[4][13];
    const float* rp = sh + ic * 169 + 2 * py * 13;
#pragma unroll
    for (int rr = 0; rr < 4; rr++)
#pragma unroll
      for (int cx = 0; cx < 13; cx++) r[rr][cx] = rp[rr * 13 + cx];
#pragma unroll
    for (int px = 0; px < 5; px++)
#pragma unroll
      for (int dy = 0; dy < 2; dy++)
#pragma unroll
        for (int dx = 0; dx < 2; dx++) {
          float s = acc[px][dy * 2 + dx];
          int x0 = 2 * px + dx;
#pragma unroll
          for (int ky = 0; ky < 3; ky++)
#pragma unroll
            for (int kx = 0; kx < 3; kx++)
              s += r[dy + ky][x0 + kx] * wv[ky * 3 + kx];
          acc[px][dy * 2 + dx] = s;
        }
  }
  float bs = bias[oc];
#pragma unroll
  for (int px = 0; px < 5; px++) {
    float m = fmaxf(fmaxf(acc[px][0], acc[px][1]), fmaxf(acc[px][2], acc[px][3]));
    out[((b * 50 + oc) * 5 + py) * 5 + px] = fmaxf(m + bs, 0.f);
  }
}

// ---------------- c33 = Linear(13->13) on last dim of h1, IN PLACE, only d1==1 ----------------
__global__ void k_c33(float* __restrict__ h1, const float* __restrict__ w,
                      const float* __restrict__ bias, const int* __restrict__ d1i) {
  int idx = blockIdx.x * 256 + threadIdx.x;
  if (idx >= BB * CC * 13) return;
  int b = idx / (CC * 13);
  if (d1i[b] != 1) return;
  float* row = h1 + b * 8450 + (idx % (CC * 13)) * 13;
  float r[13];
#pragma unroll
  for (int k = 0; k < 13; k++) r[k] = row[k];
#pragma unroll
  for (int x = 0; x < 13; x++) {
    float s = bias[x];
    const float* wx = w + x * 13;
#pragma unroll
    for (int k = 0; k < 13; k++) s += r[k] * wx[k];
    row[x] = s;
  }
}

// ---------------- conv3 on h2 (5x5 -> 3x3) + relu + pool2 -> [50,1,1]; d1==0 && d2==0 ----------------
__global__ void k_c32k(const float* __restrict__ h2, const float* __restrict__ w,
                       const float* __restrict__ bias, const int* __restrict__ d1i,
                       const int* __restrict__ d2i, float* __restrict__ c32) {
  int idx = blockIdx.x * 256 + threadIdx.x;
  if (idx >= BB * CC) return;
  int b = idx / CC, oc = idx % CC;
  if (d1i[b] != 0 || d2i[b] != 0) return;
  const float* hb = h2 + b * 1250;
  const float* wb = w + oc * 450;
  float a[4] = {0.f, 0.f, 0.f, 0.f};
  for (int ic = 0; ic < 50; ic++) {
    float r[4][4];
#pragma unroll
    for (int y = 0; y < 4; y++)
#pragma unroll
      for (int x = 0; x < 4; x++) r[y][x] = hb[ic * 25 + y * 5 + x];
    float wv[9];
#pragma unroll
    for (int i = 0; i < 9; i++) wv[i] = wb[ic * 9 + i];
#pragma unroll
    for (int py = 0; py < 2; py++)
#pragma unroll
      for (int px = 0; px < 2; px++) {
        float s = a[py * 2 + px];
#pragma unroll
        for (int ky = 0; ky < 3; ky++)
#pragma unroll
          for (int kx = 0; kx < 3; kx++)
            s += r[py + ky][px + kx] * wv[ky * 3 + kx];
        a[py * 2 + px] = s;
      }
  }
  float m = fmaxf(fmaxf(a[0], a[1]), fmaxf(a[2], a[3]));
  c32[idx] = fmaxf(m + bias[oc], 0.f);
}

// ---------------- head: per (sample, 64-row slab) of the ACTIVE branch ----------------
// out row layout per sample: [0,500)=l11, [500,666)=l12, 666=c32, [667,692)=c3d
__global__ __launch_bounds__(256) void k_head(
    const float* __restrict__ h2, const float* __restrict__ c3d,
    const float* __restrict__ c32, const float* __restrict__ p7,
    const int* __restrict__ d1i, const int* __restrict__ d2i,
    const float* __restrict__ l1w, const float* __restrict__ l1b,
    const float* __restrict__ l2w, const float* __restrict__ l2b,
    const float* __restrict__ c1l1w, const float* __restrict__ c1l1b,
    const float* __restrict__ c2l1w, const float* __restrict__ c2l1b,
    float* __restrict__ out) {
  int b = blockIdx.x >> 3;
  int slab = blockIdx.x & 7;
  int d1 = d1i[b], d2 = d2i[b];
  int branch, nrows, rstart;
  if (d1 == 2)      { branch = 0; nrows = 500; rstart = 0; }
  else if (d1 == 1) { branch = 3; nrows = 25;  rstart = 667; }
  else if (d2 == 1) { branch = 1; nrows = 166; rstart = 500; }
  else              { branch = 2; nrows = 1;   rstart = 666; }
  int roff = slab * 64;
  if (roff >= nrows) return;
  int nr = nrows - roff; if (nr > 64) nr = 64;

  __shared__ float V[64][50];
  __shared__ float red[4][64][10];
  int t = threadIdx.x;

  for (int idx = t; idx < 64 * 50; idx += 256) {
    int row = idx / 50, col = idx % 50;
    if (row < nr) {
      int rr = roff + row;
      float val;
      if (branch == 0) {
        int c = rr / 10; int j = (rr % 10) * 50 + col;
        val = p7[b * 50 + c] * c1l1w[j] + c1l1b[j];
      } else if (branch == 1) {
        int k = rr * 50 + col; int c = k / 166, tt = k % 166;
        const float* hb = h2 + (b * 50 + c) * 25;
        float m = -INFINITY;
        for (int i = 0; i < 3; i++) {
          float a0 = hb[i * 5 + 0], a1 = hb[i * 5 + 1], a2 = hb[i * 5 + 2],
                a3 = hb[i * 5 + 3], a4 = hb[i * 5 + 4];
          for (int dj = 0; dj < 3; dj++) {
            int j = 3 * tt + dj;
            const float* wj = c2l1w + j * 5;
            float s = c2l1b[j] + a0 * wj[0] + a1 * wj[1] + a2 * wj[2] + a3 * wj[3] + a4 * wj[4];
            m = fmaxf(m, s);
          }
        }
        val = m;
      } else if (branch == 2) {
        val = c32[b * 50 + col];
      } else {
        int k = rr * 50 + col; int c = k / 25, s5 = k % 25;
        val = c3d[(b * 50 + c) * 25 + s5];
      }
      V[row][col] = val;
    }
  }
  __syncthreads();

  int row = t & 63;
  int chunk = t >> 6;
  float v[50];
#pragma unroll
  for (int i = 0; i < 50; i++) v[i] = V[row][i];
  float part[10];
#pragma unroll
  for (int k = 0; k < 10; k++) part[k] = 0.f;
  int j0 = chunk * 125;
  for (int jj = 0; jj < 125; jj++) {
    int j = j0 + jj;
    const float* wr = l1w + j * 50;
    float h = l1b[j];
#pragma unroll
    for (int i = 0; i < 50; i++) h += v[i] * wr[i];
    h = fmaxf(h, 0.f);
#pragma unroll
    for (int k = 0; k < 10; k++) part[k] += h * l2w[k * 500 + j];
  }
#pragma unroll
  for (int k = 0; k < 10; k++) red[chunk][row][k] = part[k];
  __syncthreads();

  if (t < 64 && t < nr) {
    float o[10];
    float m = -INFINITY;
#pragma unroll
    for (int k = 0; k < 10; k++) {
      o[k] = red[0][t][k] + red[1][t][k] + red[2][t][k] + red[3][t][k] + l2b[k];
      m = fmaxf(m, o[k]);
    }
    float s = 0.f;
#pragma unroll
    for (int k = 0; k < 10; k++) s += expf(o[k] - m);
    float lse = m + logf(s);
    float* orow = out + (b * 692 + rstart + roff + t) * 10;
#pragma unroll
    for (int k = 0; k < 10; k++) orow[k] = o[k] - lse;
  }
}

extern "C" void kernel_launch(void* const* d_in, const int* in_sizes, int n_in,
                              void* d_out, int out_size, void* d_ws, size_t ws_size,
                              hipStream_t stream) {
  const float* x     = (const float*)d_in[0];
  const float* c1w   = (const float*)d_in[1];
  const float* c1b   = (const float*)d_in[2];
  const float* c2w   = (const float*)d_in[3];
  const float* c2b   = (const float*)d_in[4];
  const float* c3w   = (const float*)d_in[5];
  const float* c3b   = (const float*)d_in[6];
  const float* l1w   = (const float*)d_in[7];
  const float* l1b   = (const float*)d_in[8];
  const float* l2w   = (const float*)d_in[9];
  const float* l2b   = (const float*)d_in[10];
  const float* d1w   = (const float*)d_in[11];
  const float* d1b   = (const float*)d_in[12];
  const float* d2w   = (const float*)d_in[13];
  const float* d2b   = (const float*)d_in[14];
  const float* c13w  = (const float*)d_in[15];
  const float* c13b  = (const float*)d_in[16];
  const float* c1l1w = (const float*)d_in[17];
  const float* c1l1b = (const float*)d_in[18];
  const float* c2l1w = (const float*)d_in[19];
  const float* c2l1b = (const float*)d_in[20];
  float* out = (float*)d_out;

  float* ws  = (float*)d_ws;
  float* h1  = ws;                 // 4,326,400 floats
  float* h2  = h1 + 4326400;       // 640,000
  float* c3d = h2 + 640000;        // 640,000
  float* c32 = c3d + 640000;       // 25,600
  float* p7  = c32 + 25600;        // 25,600
  int*   d1i = (int*)(p7 + 25600); // 512
  int*   d2i = d1i + 512;          // 512

  float* outd1 = out + 512 * 692 * 10;        // 3,542,040
  float* outd2 = outd1 + 512;

  k_zero<<<3460, 256, 0, stream>>>(out, 885510);                 // 3,542,040/4
  k_conv1<<<16900, 256, 0, stream>>>(x, c1w, c1b, h1);
  k_d1<<<512, 256, 0, stream>>>(h1, d1w, d1b, d1i, outd1);
  k_p7<<<100, 256, 0, stream>>>(h1, p7);
  k_conv5<0><<<512, 256, 0, stream>>>(h1, c2w, c2b, d1i, h2);    // conv2 -> h2 (all samples)
  k_d2<<<512, 256, 0, stream>>>(h2, d2w, d2b, d2i, outd2);
  k_c33<<<1300, 256, 0, stream>>>(h1, c13w, c13b, d1i);          // in-place lin13 (d1==1)
  k_conv5<1><<<512, 256, 0, stream>>>(h1, c3w, c3b, d1i, c3d);   // conv3 on c33 (d1==1)
  k_c32k<<<100, 256, 0, stream>>>(h2, c3w, c3b, d1i, d2i, c32);  // conv3 on h2 (d1==0,d2==0)
  k_head<<<4096, 256, 0, stream>>>(h2, c3d, c32, p7, d1i, d2i,
                                   l1w, l1b, l2w, l2b, c1l1w, c1l1b,
                                   c2l1w, c2l1b, out);
}

// Round 2
// 417.364 us; speedup vs baseline: 2.5680x; 2.5680x over previous
//
#include <hip/hip_runtime.h>
#include <hip/hip_bf16.h>
#include <math.h>

#define BB 512
#define CC 50

// ---------------- zero-fill out[0 : 512*692*10) ----------------
__global__ void k_zero(float* __restrict__ out, int n4) {
  int i = blockIdx.x * 256 + threadIdx.x;
  if (i < n4) {
    float4 z = {0.f, 0.f, 0.f, 0.f};
    ((float4*)out)[i] = z;
  }
}

// ---------------- pack per-j head record: [w(50), b(1), l2col(10), pad(3)] = 64 floats ----------------
__global__ void k_pack(const float* __restrict__ l1w, const float* __restrict__ l1b,
                       const float* __restrict__ l2w, float* __restrict__ pack) {
  int idx = blockIdx.x * 256 + threadIdx.x;
  if (idx >= 500 * 64) return;
  int j = idx >> 6, s = idx & 63;
  float v = 0.f;
  if (s < 50) v = l1w[j * 50 + s];
  else if (s == 50) v = l1b[j];
  else if (s < 61) v = l2w[(s - 51) * 500 + j];
  pack[idx] = v;
}

// ---------------- conv1 (1->50, 3x3) + relu + pool2 -> h1[512,50,13,13] ----------------
__global__ void k_conv1(const float* __restrict__ x, const float* __restrict__ w,
                        const float* __restrict__ bias, float* __restrict__ h1) {
  int idx = blockIdx.x * 256 + threadIdx.x;
  if (idx >= BB * CC * 169) return;
  int b = idx / (CC * 169);
  int rem = idx % (CC * 169);
  int c = rem / 169;
  int p = rem % 169;
  int py = p / 13, px = p % 13;
  const float* xi = x + b * 784;
  float wr[9];
#pragma unroll
  for (int i = 0; i < 9; i++) wr[i] = w[c * 9 + i];
  float m = -INFINITY;
#pragma unroll
  for (int dy = 0; dy < 2; dy++)
#pragma unroll
    for (int dx = 0; dx < 2; dx++) {
      int y0 = 2 * py + dy, x0 = 2 * px + dx;
      float s = 0.f;
#pragma unroll
      for (int ky = 0; ky < 3; ky++)
#pragma unroll
        for (int kx = 0; kx < 3; kx++)
          s += xi[(y0 + ky) * 28 + x0 + kx] * wr[ky * 3 + kx];
      m = fmaxf(m, s);
    }
  h1[idx] = fmaxf(m + bias[c], 0.f);
}

// ---------------- router 1: argmax over 3 logits of h1 flat (8450) ----------------
__global__ void k_d1(const float* __restrict__ h1, const float* __restrict__ w,
                     const float* __restrict__ bias, int* __restrict__ d1i,
                     float* __restrict__ outd1) {
  int b = blockIdx.x, t = threadIdx.x;
  const float* hb = h1 + b * 8450;
  float s0 = 0.f, s1 = 0.f, s2 = 0.f;
  for (int i = t; i < 8450; i += 256) {
    float v = hb[i];
    s0 += v * w[i];
    s1 += v * w[8450 + i];
    s2 += v * w[16900 + i];
  }
#pragma unroll
  for (int off = 32; off >= 1; off >>= 1) {
    s0 += __shfl_down(s0, off);
    s1 += __shfl_down(s1, off);
    s2 += __shfl_down(s2, off);
  }
  __shared__ float red[4][3];
  if ((t & 63) == 0) { red[t >> 6][0] = s0; red[t >> 6][1] = s1; red[t >> 6][2] = s2; }
  __syncthreads();
  if (t == 0) {
    float l0 = bias[0], l1v = bias[1], l2v = bias[2];
    for (int wv = 0; wv < 4; wv++) { l0 += red[wv][0]; l1v += red[wv][1]; l2v += red[wv][2]; }
    int idx = 0; float best = l0;
    if (l1v > best) { best = l1v; idx = 1; }
    if (l2v > best) { best = l2v; idx = 2; }
    d1i[b] = idx;
    outd1[b] = (float)idx;
  }
}

// ---------------- router 2: argmax over 2 logits of h2 flat (1250) ----------------
__global__ void k_d2(const float* __restrict__ h2, const float* __restrict__ w,
                     const float* __restrict__ bias, int* __restrict__ d2i,
                     float* __restrict__ outd2) {
  int b = blockIdx.x, t = threadIdx.x;
  const float* hb = h2 + b * 1250;
  float s0 = 0.f, s1 = 0.f;
  for (int i = t; i < 1250; i += 256) {
    float v = hb[i];
    s0 += v * w[i];
    s1 += v * w[1250 + i];
  }
#pragma unroll
  for (int off = 32; off >= 1; off >>= 1) {
    s0 += __shfl_down(s0, off);
    s1 += __shfl_down(s1, off);
  }
  __shared__ float red[4][2];
  if ((t & 63) == 0) { red[t >> 6][0] = s0; red[t >> 6][1] = s1; }
  __syncthreads();
  if (t == 0) {
    float l0 = bias[0] + red[0][0] + red[1][0] + red[2][0] + red[3][0];
    float l1v = bias[1] + red[0][1] + red[1][1] + red[2][1] + red[3][1];
    int idx = (l1v > l0) ? 1 : 0;
    d2i[b] = idx;
    outd2[b] = (float)idx;
  }
}

// ---------------- pool7 of h1 (top-left 7x7 window only, VALID) ----------------
__global__ void k_p7(const float* __restrict__ h1, float* __restrict__ p7) {
  int idx = blockIdx.x * 256 + threadIdx.x;
  if (idx >= BB * CC) return;
  int b = idx / CC, c = idx % CC;
  const float* hp = h1 + b * 8450 + c * 169;
  float m = -INFINITY;
#pragma unroll
  for (int y = 0; y < 7; y++)
#pragma unroll
    for (int x = 0; x < 7; x++) m = fmaxf(m, hp[y * 13 + x]);
  p7[idx] = m;
}

// ---------------- 50ch 3x3 conv (13x13 -> 11x11) + relu + pool2 -> [50,5,5] ----------------
// MODE 0: always (conv2 on h1 -> h2); MODE 1: only d1==1 (conv3 on c33 -> c3d)
template <int MODE>
__global__ __launch_bounds__(256) void k_conv5(const float* __restrict__ in,
                                               const float* __restrict__ w,
                                               const float* __restrict__ bias,
                                               const int* __restrict__ d1i,
                                               float* __restrict__ out) {
  int b = blockIdx.x;
  if (MODE == 1 && d1i[b] != 1) return;
  __shared__ float sh[8450];
  for (int i = threadIdx.x; i < 8450; i += 256) sh[i] = in[b * 8450 + i];
  __syncthreads();
  int t = threadIdx.x;
  if (t >= 250) return;
  int oc = t / 5, py = t % 5;
  float acc[5][4];
#pragma unroll
  for (int i = 0; i < 5; i++)
#pragma unroll
    for (int j = 0; j < 4; j++) acc[i][j] = 0.f;
  const float* wb = w + oc * 450;
  for (int ic = 0; ic < 50; ic++) {
    float wv[9];
#pragma unroll
    for (int i = 0; i < 9; i++) wv[i] = wb[ic * 9 + i];
    float r[4][13];
    const float* rp = sh + ic * 169 + 2 * py * 13;
#pragma unroll
    for (int rr = 0; rr < 4; rr++)
#pragma unroll
      for (int cx = 0; cx < 13; cx++) r[rr][cx] = rp[rr * 13 + cx];
#pragma unroll
    for (int px = 0; px < 5; px++)
#pragma unroll
      for (int dy = 0; dy < 2; dy++)
#pragma unroll
        for (int dx = 0; dx < 2; dx++) {
          float s = acc[px][dy * 2 + dx];
          int x0 = 2 * px + dx;
#pragma unroll
          for (int ky = 0; ky < 3; ky++)
#pragma unroll
            for (int kx = 0; kx < 3; kx++)
              s += r[dy + ky][x0 + kx] * wv[ky * 3 + kx];
          acc[px][dy * 2 + dx] = s;
        }
  }
  float bs = bias[oc];
#pragma unroll
  for (int px = 0; px < 5; px++) {
    float m = fmaxf(fmaxf(acc[px][0], acc[px][1]), fmaxf(acc[px][2], acc[px][3]));
    out[((b * 50 + oc) * 5 + py) * 5 + px] = fmaxf(m + bs, 0.f);
  }
}

// ---------------- c33 = Linear(13->13) on last dim of h1, IN PLACE, only d1==1 ----------------
__global__ void k_c33(float* __restrict__ h1, const float* __restrict__ w,
                      const float* __restrict__ bias, const int* __restrict__ d1i) {
  int idx = blockIdx.x * 256 + threadIdx.x;
  if (idx >= BB * CC * 13) return;
  int b = idx / (CC * 13);
  if (d1i[b] != 1) return;
  float* row = h1 + b * 8450 + (idx % (CC * 13)) * 13;
  float r[13];
#pragma unroll
  for (int k = 0; k < 13; k++) r[k] = row[k];
#pragma unroll
  for (int x = 0; x < 13; x++) {
    float s = bias[x];
    const float* wx = w + x * 13;
#pragma unroll
    for (int k = 0; k < 13; k++) s += r[k] * wx[k];
    row[x] = s;
  }
}

// ---------------- conv3 on h2 (5x5 -> 3x3) + relu + pool2 -> [50,1,1]; d1==0 && d2==0 ----------------
__global__ void k_c32k(const float* __restrict__ h2, const float* __restrict__ w,
                       const float* __restrict__ bias, const int* __restrict__ d1i,
                       const int* __restrict__ d2i, float* __restrict__ c32) {
  int idx = blockIdx.x * 256 + threadIdx.x;
  if (idx >= BB * CC) return;
  int b = idx / CC, oc = idx % CC;
  if (d1i[b] != 0 || d2i[b] != 0) return;
  const float* hb = h2 + b * 1250;
  const float* wb = w + oc * 450;
  float a[4] = {0.f, 0.f, 0.f, 0.f};
  for (int ic = 0; ic < 50; ic++) {
    float r[4][4];
#pragma unroll
    for (int y = 0; y < 4; y++)
#pragma unroll
      for (int x = 0; x < 4; x++) r[y][x] = hb[ic * 25 + y * 5 + x];
    float wv[9];
#pragma unroll
    for (int i = 0; i < 9; i++) wv[i] = wb[ic * 9 + i];
#pragma unroll
    for (int py = 0; py < 2; py++)
#pragma unroll
      for (int px = 0; px < 2; px++) {
        float s = a[py * 2 + px];
#pragma unroll
        for (int ky = 0; ky < 3; ky++)
#pragma unroll
          for (int kx = 0; kx < 3; kx++)
            s += r[py + ky][px + kx] * wv[ky * 3 + kx];
        a[py * 2 + px] = s;
      }
  }
  float m = fmaxf(fmaxf(a[0], a[1]), fmaxf(a[2], a[3]));
  c32[idx] = fmaxf(m + bias[oc], 0.f);
}

// ---------------- head: per (sample, 64-row slab) of the ACTIVE branch ----------------
// out row layout per sample: [0,500)=l11, [500,666)=l12, 666=c32, [667,692)=c3d
// Inner loop reads weights through the scalar path: per-j packed record
// [w(50), b, l2col(10), pad(3)] at wave-uniform address (readfirstlane) ->
// compiler emits s_load_dwordx16 broadcast instead of 60 per-lane VMEM loads.
__global__ __launch_bounds__(256) void k_head(
    const float* __restrict__ h2, const float* __restrict__ c3d,
    const float* __restrict__ c32, const float* __restrict__ p7,
    const int* __restrict__ d1i, const int* __restrict__ d2i,
    const float* __restrict__ pack, const float* __restrict__ l2b,
    const float* __restrict__ c1l1w, const float* __restrict__ c1l1b,
    const float* __restrict__ c2l1w, const float* __restrict__ c2l1b,
    float* __restrict__ out) {
  int b = blockIdx.x >> 3;
  int slab = blockIdx.x & 7;
  int d1 = d1i[b], d2 = d2i[b];
  int branch, nrows, rstart;
  if (d1 == 2)      { branch = 0; nrows = 500; rstart = 0; }
  else if (d1 == 1) { branch = 3; nrows = 25;  rstart = 667; }
  else if (d2 == 1) { branch = 1; nrows = 166; rstart = 500; }
  else              { branch = 2; nrows = 1;   rstart = 666; }
  int roff = slab * 64;
  if (roff >= nrows) return;
  int nr = nrows - roff; if (nr > 64) nr = 64;

  __shared__ float V[64][52];
  __shared__ float red[4][64][10];
  int t = threadIdx.x;

  for (int idx = t; idx < 64 * 50; idx += 256) {
    int row = idx / 50, col = idx % 50;
    if (row < nr) {
      int rr = roff + row;
      float val;
      if (branch == 0) {
        int c = rr / 10; int j = (rr % 10) * 50 + col;
        val = p7[b * 50 + c] * c1l1w[j] + c1l1b[j];
      } else if (branch == 1) {
        int k = rr * 50 + col; int c = k / 166, tt = k % 166;
        const float* hb = h2 + (b * 50 + c) * 25;
        float m = -INFINITY;
        for (int i = 0; i < 3; i++) {
          float a0 = hb[i * 5 + 0], a1 = hb[i * 5 + 1], a2 = hb[i * 5 + 2],
                a3 = hb[i * 5 + 3], a4 = hb[i * 5 + 4];
          for (int dj = 0; dj < 3; dj++) {
            int j = 3 * tt + dj;
            const float* wj = c2l1w + j * 5;
            float s = c2l1b[j] + a0 * wj[0] + a1 * wj[1] + a2 * wj[2] + a3 * wj[3] + a4 * wj[4];
            m = fmaxf(m, s);
          }
        }
        val = m;
      } else if (branch == 2) {
        val = c32[b * 50 + col];
      } else {
        int k = rr * 50 + col; int c = k / 25, s5 = k % 25;
        val = c3d[(b * 50 + c) * 25 + s5];
      }
      V[row][col] = val;
    }
  }
  __syncthreads();

  int row = t & 63;
  int chunk = t >> 6;
  float v[50];
#pragma unroll
  for (int i = 0; i < 50; i++) v[i] = V[row][i];
  float part[10];
#pragma unroll
  for (int k = 0; k < 10; k++) part[k] = 0.f;
  int j0 = __builtin_amdgcn_readfirstlane(chunk * 125);
  for (int jj = 0; jj < 125; jj++) {
    const float* rec = pack + (j0 + jj) * 64;   // wave-uniform -> s_load path
    float h = rec[50];
#pragma unroll
    for (int i = 0; i < 50; i++) h += v[i] * rec[i];
    h = fmaxf(h, 0.f);
#pragma unroll
    for (int k = 0; k < 10; k++) part[k] += h * rec[51 + k];
  }
#pragma unroll
  for (int k = 0; k < 10; k++) red[chunk][row][k] = part[k];
  __syncthreads();

  if (t < 64 && t < nr) {
    float o[10];
    float m = -INFINITY;
#pragma unroll
    for (int k = 0; k < 10; k++) {
      o[k] = red[0][t][k] + red[1][t][k] + red[2][t][k] + red[3][t][k] + l2b[k];
      m = fmaxf(m, o[k]);
    }
    float s = 0.f;
#pragma unroll
    for (int k = 0; k < 10; k++) s += expf(o[k] - m);
    float lse = m + logf(s);
    float* orow = out + (b * 692 + rstart + roff + t) * 10;
#pragma unroll
    for (int k = 0; k < 10; k++) orow[k] = o[k] - lse;
  }
}

extern "C" void kernel_launch(void* const* d_in, const int* in_sizes, int n_in,
                              void* d_out, int out_size, void* d_ws, size_t ws_size,
                              hipStream_t stream) {
  const float* x     = (const float*)d_in[0];
  const float* c1w   = (const float*)d_in[1];
  const float* c1b   = (const float*)d_in[2];
  const float* c2w   = (const float*)d_in[3];
  const float* c2b   = (const float*)d_in[4];
  const float* c3w   = (const float*)d_in[5];
  const float* c3b   = (const float*)d_in[6];
  const float* l1w   = (const float*)d_in[7];
  const float* l1b   = (const float*)d_in[8];
  const float* l2w   = (const float*)d_in[9];
  const float* l2b   = (const float*)d_in[10];
  const float* d1w   = (const float*)d_in[11];
  const float* d1b   = (const float*)d_in[12];
  const float* d2w   = (const float*)d_in[13];
  const float* d2b   = (const float*)d_in[14];
  const float* c13w  = (const float*)d_in[15];
  const float* c13b  = (const float*)d_in[16];
  const float* c1l1w = (const float*)d_in[17];
  const float* c1l1b = (const float*)d_in[18];
  const float* c2l1w = (const float*)d_in[19];
  const float* c2l1b = (const float*)d_in[20];
  float* out = (float*)d_out;

  float* ws  = (float*)d_ws;
  float* h1  = ws;                 // 4,326,400 floats
  float* h2  = h1 + 4326400;       // 640,000
  float* c3d = h2 + 640000;        // 640,000
  float* c32 = c3d + 640000;       // 25,600
  float* p7  = c32 + 25600;        // 25,600
  int*   d1i = (int*)(p7 + 25600); // 512
  int*   d2i = d1i + 512;          // 512
  float* pack = (float*)(d2i + 512); // 32,000 floats (500 x 64)

  float* outd1 = out + 512 * 692 * 10;        // 3,542,040
  float* outd2 = outd1 + 512;

  k_zero<<<3460, 256, 0, stream>>>(out, 885510);                 // 3,542,040/4
  k_pack<<<125, 256, 0, stream>>>(l1w, l1b, l2w, pack);
  k_conv1<<<16900, 256, 0, stream>>>(x, c1w, c1b, h1);
  k_d1<<<512, 256, 0, stream>>>(h1, d1w, d1b, d1i, outd1);
  k_p7<<<100, 256, 0, stream>>>(h1, p7);
  k_conv5<0><<<512, 256, 0, stream>>>(h1, c2w, c2b, d1i, h2);    // conv2 -> h2 (all samples)
  k_d2<<<512, 256, 0, stream>>>(h2, d2w, d2b, d2i, outd2);
  k_c33<<<1300, 256, 0, stream>>>(h1, c13w, c13b, d1i);          // in-place lin13 (d1==1)
  k_conv5<1><<<512, 256, 0, stream>>>(h1, c3w, c3b, d1i, c3d);   // conv3 on c33 (d1==1)
  k_c32k<<<100, 256, 0, stream>>>(h2, c3w, c3b, d1i, d2i, c32);  // conv3 on h2 (d1==0,d2==0)
  k_head<<<4096, 256, 0, stream>>>(h2, c3d, c32, p7, d1i, d2i,
                                   pack, l2b, c1l1w, c1l1b,
                                   c2l1w, c2l1b, out);
}

// Round 3
// 367.572 us; speedup vs baseline: 2.9159x; 1.1355x over previous
//
#include <hip/hip_runtime.h>
#include <hip/hip_bf16.h>
#include <math.h>

#define BB 512
#define CC 50

// ---------------- zero-fill out[0 : 512*692*10) ----------------
__global__ void k_zero(float* __restrict__ out, int n4) {
  int i = blockIdx.x * 256 + threadIdx.x;
  if (i < n4) {
    float4 z = {0.f, 0.f, 0.f, 0.f};
    ((float4*)out)[i] = z;
  }
}

// ---------------- pack per-j head record: [w(50), b(1), l2col(10), pad(3)] = 64 floats ----------------
__global__ void k_pack(const float* __restrict__ l1w, const float* __restrict__ l1b,
                       const float* __restrict__ l2w, float* __restrict__ pack) {
  int idx = blockIdx.x * 256 + threadIdx.x;
  if (idx >= 500 * 64) return;
  int j = idx >> 6, s = idx & 63;
  float v = 0.f;
  if (s < 50) v = l1w[j * 50 + s];
  else if (s == 50) v = l1b[j];
  else if (s < 61) v = l2w[(s - 51) * 500 + j];
  pack[idx] = v;
}

// ---------------- conv1 (1->50, 3x3) + relu + pool2 -> h1[512,50,13,13] ----------------
__global__ void k_conv1(const float* __restrict__ x, const float* __restrict__ w,
                        const float* __restrict__ bias, float* __restrict__ h1) {
  int idx = blockIdx.x * 256 + threadIdx.x;
  if (idx >= BB * CC * 169) return;
  int b = idx / (CC * 169);
  int rem = idx % (CC * 169);
  int c = rem / 169;
  int p = rem % 169;
  int py = p / 13, px = p % 13;
  const float* xi = x + b * 784;
  float wr[9];
#pragma unroll
  for (int i = 0; i < 9; i++) wr[i] = w[c * 9 + i];
  float m = -INFINITY;
#pragma unroll
  for (int dy = 0; dy < 2; dy++)
#pragma unroll
    for (int dx = 0; dx < 2; dx++) {
      int y0 = 2 * py + dy, x0 = 2 * px + dx;
      float s = 0.f;
#pragma unroll
      for (int ky = 0; ky < 3; ky++)
#pragma unroll
        for (int kx = 0; kx < 3; kx++)
          s += xi[(y0 + ky) * 28 + x0 + kx] * wr[ky * 3 + kx];
      m = fmaxf(m, s);
    }
  h1[idx] = fmaxf(m + bias[c], 0.f);
}

// ---------------- router 1: argmax over 3 logits of h1 flat (8450) ----------------
__global__ void k_d1(const float* __restrict__ h1, const float* __restrict__ w,
                     const float* __restrict__ bias, int* __restrict__ d1i,
                     float* __restrict__ outd1) {
  int b = blockIdx.x, t = threadIdx.x;
  const float* hb = h1 + b * 8450;
  float s0 = 0.f, s1 = 0.f, s2 = 0.f;
  for (int i = t; i < 8450; i += 256) {
    float v = hb[i];
    s0 += v * w[i];
    s1 += v * w[8450 + i];
    s2 += v * w[16900 + i];
  }
#pragma unroll
  for (int off = 32; off >= 1; off >>= 1) {
    s0 += __shfl_down(s0, off);
    s1 += __shfl_down(s1, off);
    s2 += __shfl_down(s2, off);
  }
  __shared__ float red[4][3];
  if ((t & 63) == 0) { red[t >> 6][0] = s0; red[t >> 6][1] = s1; red[t >> 6][2] = s2; }
  __syncthreads();
  if (t == 0) {
    float l0 = bias[0], l1v = bias[1], l2v = bias[2];
    for (int wv = 0; wv < 4; wv++) { l0 += red[wv][0]; l1v += red[wv][1]; l2v += red[wv][2]; }
    int idx = 0; float best = l0;
    if (l1v > best) { best = l1v; idx = 1; }
    if (l2v > best) { best = l2v; idx = 2; }
    d1i[b] = idx;
    outd1[b] = (float)idx;
  }
}

// ---------------- router 2: argmax over 2 logits of h2 flat (1250) ----------------
__global__ void k_d2(const float* __restrict__ h2, const float* __restrict__ w,
                     const float* __restrict__ bias, int* __restrict__ d2i,
                     float* __restrict__ outd2) {
  int b = blockIdx.x, t = threadIdx.x;
  const float* hb = h2 + b * 1250;
  float s0 = 0.f, s1 = 0.f;
  for (int i = t; i < 1250; i += 256) {
    float v = hb[i];
    s0 += v * w[i];
    s1 += v * w[1250 + i];
  }
#pragma unroll
  for (int off = 32; off >= 1; off >>= 1) {
    s0 += __shfl_down(s0, off);
    s1 += __shfl_down(s1, off);
  }
  __shared__ float red[4][2];
  if ((t & 63) == 0) { red[t >> 6][0] = s0; red[t >> 6][1] = s1; }
  __syncthreads();
  if (t == 0) {
    float l0 = bias[0] + red[0][0] + red[1][0] + red[2][0] + red[3][0];
    float l1v = bias[1] + red[0][1] + red[1][1] + red[2][1] + red[3][1];
    int idx = (l1v > l0) ? 1 : 0;
    d2i[b] = idx;
    outd2[b] = (float)idx;
  }
}

// ---------------- pool7 of h1 (top-left 7x7 window only, VALID) ----------------
__global__ void k_p7(const float* __restrict__ h1, float* __restrict__ p7) {
  int idx = blockIdx.x * 256 + threadIdx.x;
  if (idx >= BB * CC) return;
  int b = idx / CC, c = idx % CC;
  const float* hp = h1 + b * 8450 + c * 169;
  float m = -INFINITY;
#pragma unroll
  for (int y = 0; y < 7; y++)
#pragma unroll
    for (int x = 0; x < 7; x++) m = fmaxf(m, hp[y * 13 + x]);
  p7[idx] = m;
}

// ---------------- 50ch 3x3 conv (13x13 -> 11x11) + relu + pool2 -> [50,5,5] ----------------
// MODE 0: always (conv2 on h1 -> h2); MODE 1: only d1==1 (conv3 on c33 -> c3d)
template <int MODE>
__global__ __launch_bounds__(256) void k_conv5(const float* __restrict__ in,
                                               const float* __restrict__ w,
                                               const float* __restrict__ bias,
                                               const int* __restrict__ d1i,
                                               float* __restrict__ out) {
  int b = blockIdx.x;
  if (MODE == 1 && d1i[b] != 1) return;
  __shared__ float sh[8450];
  for (int i = threadIdx.x; i < 8450; i += 256) sh[i] = in[b * 8450 + i];
  __syncthreads();
  int t = threadIdx.x;
  if (t >= 250) return;
  int oc = t / 5, py = t % 5;
  float acc[5][4];
#pragma unroll
  for (int i = 0; i < 5; i++)
#pragma unroll
    for (int j = 0; j < 4; j++) acc[i][j] = 0.f;
  const float* wb = w + oc * 450;
  for (int ic = 0; ic < 50; ic++) {
    float wv[9];
#pragma unroll
    for (int i = 0; i < 9; i++) wv[i] = wb[ic * 9 + i];
    float r[4][13];
    const float* rp = sh + ic * 169 + 2 * py * 13;
#pragma unroll
    for (int rr = 0; rr < 4; rr++)
#pragma unroll
      for (int cx = 0; cx < 13; cx++) r[rr][cx] = rp[rr * 13 + cx];
#pragma unroll
    for (int px = 0; px < 5; px++)
#pragma unroll
      for (int dy = 0; dy < 2; dy++)
#pragma unroll
        for (int dx = 0; dx < 2; dx++) {
          float s = acc[px][dy * 2 + dx];
          int x0 = 2 * px + dx;
#pragma unroll
          for (int ky = 0; ky < 3; ky++)
#pragma unroll
            for (int kx = 0; kx < 3; kx++)
              s += r[dy + ky][x0 + kx] * wv[ky * 3 + kx];
          acc[px][dy * 2 + dx] = s;
        }
  }
  float bs = bias[oc];
#pragma unroll
  for (int px = 0; px < 5; px++) {
    float m = fmaxf(fmaxf(acc[px][0], acc[px][1]), fmaxf(acc[px][2], acc[px][3]));
    out[((b * 50 + oc) * 5 + py) * 5 + px] = fmaxf(m + bs, 0.f);
  }
}

// ---------------- c33 = Linear(13->13) on last dim of h1, IN PLACE, only d1==1 ----------------
__global__ void k_c33(float* __restrict__ h1, const float* __restrict__ w,
                      const float* __restrict__ bias, const int* __restrict__ d1i) {
  int idx = blockIdx.x * 256 + threadIdx.x;
  if (idx >= BB * CC * 13) return;
  int b = idx / (CC * 13);
  if (d1i[b] != 1) return;
  float* row = h1 + b * 8450 + (idx % (CC * 13)) * 13;
  float r[13];
#pragma unroll
  for (int k = 0; k < 13; k++) r[k] = row[k];
#pragma unroll
  for (int x = 0; x < 13; x++) {
    float s = bias[x];
    const float* wx = w + x * 13;
#pragma unroll
    for (int k = 0; k < 13; k++) s += r[k] * wx[k];
    row[x] = s;
  }
}

// ---------------- conv3 on h2 (5x5 -> 3x3) + relu + pool2 -> [50,1,1]; d1==0 && d2==0 ----------------
__global__ void k_c32k(const float* __restrict__ h2, const float* __restrict__ w,
                       const float* __restrict__ bias, const int* __restrict__ d1i,
                       const int* __restrict__ d2i, float* __restrict__ c32) {
  int idx = blockIdx.x * 256 + threadIdx.x;
  if (idx >= BB * CC) return;
  int b = idx / CC, oc = idx % CC;
  if (d1i[b] != 0 || d2i[b] != 0) return;
  const float* hb = h2 + b * 1250;
  const float* wb = w + oc * 450;
  float a[4] = {0.f, 0.f, 0.f, 0.f};
  for (int ic = 0; ic < 50; ic++) {
    float r[4][4];
#pragma unroll
    for (int y = 0; y < 4; y++)
#pragma unroll
      for (int x = 0; x < 4; x++) r[y][x] = hb[ic * 25 + y * 5 + x];
    float wv[9];
#pragma unroll
    for (int i = 0; i < 9; i++) wv[i] = wb[ic * 9 + i];
#pragma unroll
    for (int py = 0; py < 2; py++)
#pragma unroll
      for (int px = 0; px < 2; px++) {
        float s = a[py * 2 + px];
#pragma unroll
        for (int ky = 0; ky < 3; ky++)
#pragma unroll
          for (int kx = 0; kx < 3; kx++)
            s += r[py + ky][px + kx] * wv[ky * 3 + kx];
        a[py * 2 + px] = s;
      }
  }
  float m = fmaxf(fmaxf(a[0], a[1]), fmaxf(a[2], a[3]));
  c32[idx] = fmaxf(m + bias[oc], 0.f);
}

// ---------------- head: per (sample, 64-row slab) of the ACTIVE branch ----------------
// out row layout per sample: [0,500)=l11, [500,666)=l12, 666=c32, [667,692)=c3d
// Weights stream through the scalar (SMEM) path via wave-uniform packed records;
// the 50-dot is split into 4 independent partial chains to break the FP-ordered
// dependent-FMA latency chain (reassociation OK: absmax 0.03 vs thr 0.39).
__global__ __launch_bounds__(256) void k_head(
    const float* __restrict__ h2, const float* __restrict__ c3d,
    const float* __restrict__ c32, const float* __restrict__ p7,
    const int* __restrict__ d1i, const int* __restrict__ d2i,
    const float* __restrict__ pack, const float* __restrict__ l2b,
    const float* __restrict__ c1l1w, const float* __restrict__ c1l1b,
    const float* __restrict__ c2l1w, const float* __restrict__ c2l1b,
    float* __restrict__ out) {
  int b = blockIdx.x >> 3;
  int slab = blockIdx.x & 7;
  int d1 = d1i[b], d2 = d2i[b];
  int branch, nrows, rstart;
  if (d1 == 2)      { branch = 0; nrows = 500; rstart = 0; }
  else if (d1 == 1) { branch = 3; nrows = 25;  rstart = 667; }
  else if (d2 == 1) { branch = 1; nrows = 166; rstart = 500; }
  else              { branch = 2; nrows = 1;   rstart = 666; }
  int roff = slab * 64;
  if (roff >= nrows) return;
  int nr = nrows - roff; if (nr > 64) nr = 64;

  __shared__ float V[64][51];   // stride 51: coprime with 32 banks -> free 2-way on v[] fill
  __shared__ float red[4][64][11];
  int t = threadIdx.x;

  for (int idx = t; idx < 64 * 50; idx += 256) {
    int row = idx / 50, col = idx % 50;
    if (row < nr) {
      int rr = roff + row;
      float val;
      if (branch == 0) {
        int c = rr / 10; int j = (rr % 10) * 50 + col;
        val = p7[b * 50 + c] * c1l1w[j] + c1l1b[j];
      } else if (branch == 1) {
        int k = rr * 50 + col; int c = k / 166, tt = k % 166;
        const float* hb = h2 + (b * 50 + c) * 25;
        float m = -INFINITY;
        for (int i = 0; i < 3; i++) {
          float a0 = hb[i * 5 + 0], a1 = hb[i * 5 + 1], a2 = hb[i * 5 + 2],
                a3 = hb[i * 5 + 3], a4 = hb[i * 5 + 4];
          for (int dj = 0; dj < 3; dj++) {
            int j = 3 * tt + dj;
            const float* wj = c2l1w + j * 5;
            float s = c2l1b[j] + a0 * wj[0] + a1 * wj[1] + a2 * wj[2] + a3 * wj[3] + a4 * wj[4];
            m = fmaxf(m, s);
          }
        }
        val = m;
      } else if (branch == 2) {
        val = c32[b * 50 + col];
      } else {
        int k = rr * 50 + col; int c = k / 25, s5 = k % 25;
        val = c3d[(b * 50 + c) * 25 + s5];
      }
      V[row][col] = val;
    }
  }
  __syncthreads();

  int row = t & 63;
  int chunk = t >> 6;
  float v[50];
#pragma unroll
  for (int i = 0; i < 50; i++) v[i] = V[row][i];
  float part[10];
#pragma unroll
  for (int k = 0; k < 10; k++) part[k] = 0.f;
  int j0 = __builtin_amdgcn_readfirstlane(chunk * 125);
#pragma unroll 2
  for (int jj = 0; jj < 125; jj++) {
    const float* rec = pack + (j0 + jj) * 64;   // wave-uniform -> s_load path
    float h0 = 0.f, h1 = 0.f, h2s = 0.f, h3 = 0.f;
#pragma unroll
    for (int i = 0; i < 48; i += 4) {
      h0 += v[i + 0] * rec[i + 0];
      h1 += v[i + 1] * rec[i + 1];
      h2s += v[i + 2] * rec[i + 2];
      h3 += v[i + 3] * rec[i + 3];
    }
    h0 += v[48] * rec[48];
    h1 += v[49] * rec[49];
    float h = ((h0 + h2s) + (h1 + h3)) + rec[50];
    h = fmaxf(h, 0.f);
#pragma unroll
    for (int k = 0; k < 10; k++) part[k] += h * rec[51 + k];
  }
#pragma unroll
  for (int k = 0; k < 10; k++) red[chunk][row][k] = part[k];
  __syncthreads();

  if (t < 64 && t < nr) {
    float o[10];
    float m = -INFINITY;
#pragma unroll
    for (int k = 0; k < 10; k++) {
      o[k] = red[0][t][k] + red[1][t][k] + red[2][t][k] + red[3][t][k] + l2b[k];
      m = fmaxf(m, o[k]);
    }
    float s = 0.f;
#pragma unroll
    for (int k = 0; k < 10; k++) s += expf(o[k] - m);
    float lse = m + logf(s);
    float* orow = out + (b * 692 + rstart + roff + t) * 10;
#pragma unroll
    for (int k = 0; k < 10; k++) orow[k] = o[k] - lse;
  }
}

extern "C" void kernel_launch(void* const* d_in, const int* in_sizes, int n_in,
                              void* d_out, int out_size, void* d_ws, size_t ws_size,
                              hipStream_t stream) {
  const float* x     = (const float*)d_in[0];
  const float* c1w   = (const float*)d_in[1];
  const float* c1b   = (const float*)d_in[2];
  const float* c2w   = (const float*)d_in[3];
  const float* c2b   = (const float*)d_in[4];
  const float* c3w   = (const float*)d_in[5];
  const float* c3b   = (const float*)d_in[6];
  const float* l1w   = (const float*)d_in[7];
  const float* l1b   = (const float*)d_in[8];
  const float* l2w   = (const float*)d_in[9];
  const float* l2b   = (const float*)d_in[10];
  const float* d1w   = (const float*)d_in[11];
  const float* d1b   = (const float*)d_in[12];
  const float* d2w   = (const float*)d_in[13];
  const float* d2b   = (const float*)d_in[14];
  const float* c13w  = (const float*)d_in[15];
  const float* c13b  = (const float*)d_in[16];
  const float* c1l1w = (const float*)d_in[17];
  const float* c1l1b = (const float*)d_in[18];
  const float* c2l1w = (const float*)d_in[19];
  const float* c2l1b = (const float*)d_in[20];
  float* out = (float*)d_out;

  float* ws  = (float*)d_ws;
  float* h1  = ws;                 // 4,326,400 floats
  float* h2  = h1 + 4326400;       // 640,000
  float* c3d = h2 + 640000;        // 640,000
  float* c32 = c3d + 640000;       // 25,600
  float* p7  = c32 + 25600;        // 25,600
  int*   d1i = (int*)(p7 + 25600); // 512
  int*   d2i = d1i + 512;          // 512
  float* pack = (float*)(d2i + 512); // 32,000 floats (500 x 64)

  float* outd1 = out + 512 * 692 * 10;        // 3,542,040
  float* outd2 = outd1 + 512;

  k_zero<<<3460, 256, 0, stream>>>(out, 885510);                 // 3,542,040/4
  k_pack<<<125, 256, 0, stream>>>(l1w, l1b, l2w, pack);
  k_conv1<<<16900, 256, 0, stream>>>(x, c1w, c1b, h1);
  k_d1<<<512, 256, 0, stream>>>(h1, d1w, d1b, d1i, outd1);
  k_p7<<<100, 256, 0, stream>>>(h1, p7);
  k_conv5<0><<<512, 256, 0, stream>>>(h1, c2w, c2b, d1i, h2);    // conv2 -> h2 (all samples)
  k_d2<<<512, 256, 0, stream>>>(h2, d2w, d2b, d2i, outd2);
  k_c33<<<1300, 256, 0, stream>>>(h1, c13w, c13b, d1i);          // in-place lin13 (d1==1)
  k_conv5<1><<<512, 256, 0, stream>>>(h1, c3w, c3b, d1i, c3d);   // conv3 on c33 (d1==1)
  k_c32k<<<100, 256, 0, stream>>>(h2, c3w, c3b, d1i, d2i, c32);  // conv3 on h2 (d1==0,d2==0)
  k_head<<<4096, 256, 0, stream>>>(h2, c3d, c32, p7, d1i, d2i,
                                   pack, l2b, c1l1w, c1l1b,
                                   c2l1w, c2l1b, out);
}